// Round 7
// baseline (279.735 us; speedup 1.0000x reference)
//
#include <hip/hip_runtime.h>
#include <hip/hip_bf16.h>

#define RREL 4
#define DIM 256
#define KDIM 1280      // 4*DIM (means) + DIM (self)
#define KMEAN 1024     // means-only K extent
#define BCAP 32        // bucket capacity per (r,dst) segment

__device__ __forceinline__ float bf2f(unsigned short u) {
    union { unsigned int i; float f; } z; z.i = ((unsigned int)u) << 16; return z.f;
}
__device__ __forceinline__ unsigned short f2bf(float f) {
    __hip_bfloat16 h = __float2bfloat16(f);
    return *(unsigned short*)&h;
}

typedef __attribute__((ext_vector_type(8))) short bf16x8;
typedef __attribute__((ext_vector_type(8))) unsigned short u16x8;
typedef __attribute__((ext_vector_type(4))) float f32x4;
typedef __attribute__((ext_vector_type(4))) float fx4;

// ---------------- fused prep: bucket-scatter + x->bf16 cast + W0 transpose ----------

__global__ __launch_bounds__(256)
void prep(const int* __restrict__ etype, const int* __restrict__ src,
          const int* __restrict__ dst,
          int* __restrict__ counts, int* __restrict__ bucket, int N, int E,
          const float* __restrict__ x, __hip_bfloat16* __restrict__ xb, int n4,
          const float* __restrict__ W0, const float* __restrict__ root0,
          __hip_bfloat16* __restrict__ WT,
          int eb, int cb) {
    int b = blockIdx.x;
    if (b < eb) {                       // count + scatter into buckets
        int e = b * 256 + threadIdx.x;
        if (e < E) {
            int seg = etype[e] * N + dst[e];
            int p = atomicAdd(&counts[seg], 1);
            if (p < BCAP) bucket[(size_t)seg * BCAP + p] = src[e];
        }
    } else if (b < eb + cb) {           // cast x -> bf16
        int i = (b - eb) * 256 + threadIdx.x;
        if (i < n4) {
            fx4 v = *((const fx4*)x + i);
            ushort4 u = make_ushort4(f2bf(v.x), f2bf(v.y), f2bf(v.z), f2bf(v.w));
            ((ushort4*)xb)[i] = u;
        }
    } else {                            // WT[n=0..255][k=0..1279] n-major (layer 0)
        __shared__ float tile[32][33];
        int q = b - eb - cb;            // 0..319
        int nblk = q / 40;              // 0..7   (n0 over 256)
        int kblk = q - nblk * 40;       // 0..39  (k0 over 1280)
        int k0 = kblk * 32, n0 = nblk * 32;
        int tx = threadIdx.x & 31, ty = threadIdx.x >> 5;   // 32x8
        const float* srcp;
        int kbase;
        if (k0 < RREL * DIM) { srcp = W0; kbase = k0; } else { srcp = root0; kbase = k0 - RREL * DIM; }
#pragma unroll
        for (int j = 0; j < 4; j++) {
            int k = kbase + ty + j * 8;
            tile[ty + j * 8][tx] = srcp[(size_t)k * DIM + n0 + tx];
        }
        __syncthreads();
#pragma unroll
        for (int j = 0; j < 4; j++) {
            int n = n0 + ty + j * 8;
            WT[(size_t)n * KDIM + k0 + tx] = __float2bfloat16(tile[tx][ty + j * 8]);
        }
    }
}

// ---------------- edge weights for collapsed layer 1 (needs final counts) ----------
// w(s,r) += 1/cnt(r,dst) per edge. Feeds the fused GEMM epilogue.

__global__ __launch_bounds__(256)
void edgew(const int* __restrict__ etype, const int* __restrict__ srcv,
           const int* __restrict__ dstv, const int* __restrict__ counts,
           float* __restrict__ wsr, int N, int E) {
    int e = blockIdx.x * 256 + threadIdx.x;
    if (e < E) {
        int r = etype[e];
        int seg = r * N + dstv[e];
        float sc = 1.f / (float)counts[seg];
        atomicAdd(&wsr[(size_t)srcv[e] * RREL + r], sc);
    }
}

// ---------------- FUSED: mean-gather + MFMA GEMM + collapsed-layer-1 epilogue --------
// The Y[N,1024] intermediate never exists: for K-steps 0..15 (relation r=k>>2, dim
// slice d0=(k&3)*64) the A-tile is the per-relation neighbor mean, computed by 256
// threads (thread = (row i=t>>2, 16-dim chunk td=t&3)) gathering xb slices and
// ds_writing bf16 means into As with the MFMA-matching XOR swizzle. K-steps 16..19
// stage xb directly via global_load_lds (R6 path). Saves aggregate's Y write + gemm's
// Y read + one dispatch; gather latency hides under MFMA + B staging.
// Relation quads q_r[4]/cnt_r[4] prefetched once per block (row fixed per thread)
// -> no counts->bucket->slice chain in the loop. Rows >= N: cnt=0 (writes zeros).
// vmcnt order: gather loads issued BEFORE B's gll so the compiler's gather wait is
// vmcnt(4) (B stays in flight); end-of-iter vmcnt(0) is ~500cy after B issue = cheap.
// Full unroll keeps q_r[r] / buffer parity compile-time (no scratch, rule 20).
//   sv[r*256+c] += sum_rows wsr[row][r] * relu_h1[row][c];  sv[4*256+c] += sum relu_h1

#define BMg 64
#define BNg 128
#define BKg 64
#define NKS 20

__global__ __launch_bounds__(256, 3)
void gemm_fused(const __hip_bfloat16* __restrict__ xb,   // [Mpad, 256] features
                const int* __restrict__ counts,          // [4N]
                const int* __restrict__ bucket,          // [4N][32]
                const __hip_bfloat16* __restrict__ Bt,   // [256, 1280] n-major
                const float* __restrict__ bias,          // [256]
                const float* __restrict__ wsr,           // [N, 4]
                float* __restrict__ sv,                  // [5*256]
                int N) {
    __shared__ short As[2][BMg * BKg];       // 2 x 8 KB
    __shared__ short Bs[2][BNg * BKg];       // 2 x 16 KB  (48 KB total -> 3 blocks/CU)
    int t = threadIdx.x;
    int lane = t & 63;
    int w = t >> 6;
    int nh = blockIdx.x & 1;
    size_t row0 = (size_t)(blockIdx.x >> 1) * BMg;
    int ncol0 = nh * BNg;

    const unsigned short* fu = (const unsigned short*)xb;
    const unsigned short* Bg = (const unsigned short*)Bt;

    // ---- per-thread gather identity (fixed all kernel) ----
    int gi = t >> 2, td = t & 3;             // row-in-tile, 16-dim chunk
    size_t grow = row0 + gi;
    int cnt_r[4];
    int4 q_r[4];
#pragma unroll
    for (int r = 0; r < 4; r++) {
        cnt_r[r] = 0;
        if (grow < (size_t)N) cnt_r[r] = min(counts[r * N + (int)grow], BCAP);
    }
#pragma unroll
    for (int r = 0; r < 4; r++) {
        q_r[r] = make_int4(0, 0, 0, 0);
        if (cnt_r[r] > 0)
            q_r[r] = *(const int4*)(bucket + ((size_t)r * N + grow) * BCAP);
    }

    float bb[2];
#pragma unroll
    for (int ni = 0; ni < 2; ni++) bb[ni] = bias[ncol0 + w * 32 + ni * 16 + (lane & 15)];

    f32x4 acc[4][2] = {};

    struct G8 { u16x8 v0, v1, v2, v3, v4, v5, v6, v7; float m1, m2, m3; };

    auto g_issue = [&](int s, G8& g) {      // s compile-time under unroll
        int r = s >> 2, d0 = (s & 3) * 64;
        int c = cnt_r[r];
        if (c > 0) {
            int4 q = q_r[r];
            g.m1 = (1 < c) ? 1.f : 0.f;
            g.m2 = (2 < c) ? 1.f : 0.f;
            g.m3 = (3 < c) ? 1.f : 0.f;
            int i0 = q.x;
            int i1 = g.m1 ? q.y : q.x;
            int i2 = g.m2 ? q.z : q.x;
            int i3 = g.m3 ? q.w : q.x;
            const unsigned short* p0 = fu + (size_t)i0 * DIM + d0 + td * 16;
            const unsigned short* p1 = fu + (size_t)i1 * DIM + d0 + td * 16;
            const unsigned short* p2 = fu + (size_t)i2 * DIM + d0 + td * 16;
            const unsigned short* p3 = fu + (size_t)i3 * DIM + d0 + td * 16;
            g.v0 = *(const u16x8*)p0;  g.v1 = *(const u16x8*)(p0 + 8);
            g.v2 = *(const u16x8*)p1;  g.v3 = *(const u16x8*)(p1 + 8);
            g.v4 = *(const u16x8*)p2;  g.v5 = *(const u16x8*)(p2 + 8);
            g.v6 = *(const u16x8*)p3;  g.v7 = *(const u16x8*)(p3 + 8);
        }
    };

    auto g_finish = [&](int s, G8& g, short* as) {
        int r = s >> 2, d0 = (s & 3) * 64;
        int c = cnt_r[r];
        float a[16] = {};
        if (c > 0) {
#pragma unroll
            for (int j = 0; j < 8; j++) {
                a[j]     += bf2f(g.v0[j]) + g.m1 * bf2f(g.v2[j]) + g.m2 * bf2f(g.v4[j]) + g.m3 * bf2f(g.v6[j]);
                a[8 + j] += bf2f(g.v1[j]) + g.m1 * bf2f(g.v3[j]) + g.m2 * bf2f(g.v5[j]) + g.m3 * bf2f(g.v7[j]);
            }
            const int* bk = bucket + ((size_t)r * N + grow) * BCAP;
            for (int kq = 4; kq < c; kq += 4) {    // rare (cnt>4) serial tail
                int4 q = *(const int4*)(bk + kq);
                float n1 = (kq + 1 < c) ? 1.f : 0.f;
                float n2 = (kq + 2 < c) ? 1.f : 0.f;
                float n3 = (kq + 3 < c) ? 1.f : 0.f;
                int i0 = q.x, i1 = n1 ? q.y : q.x, i2 = n2 ? q.z : q.x, i3 = n3 ? q.w : q.x;
                const unsigned short* p0 = fu + (size_t)i0 * DIM + d0 + td * 16;
                const unsigned short* p1 = fu + (size_t)i1 * DIM + d0 + td * 16;
                const unsigned short* p2 = fu + (size_t)i2 * DIM + d0 + td * 16;
                const unsigned short* p3 = fu + (size_t)i3 * DIM + d0 + td * 16;
                u16x8 u0 = *(const u16x8*)p0, u1 = *(const u16x8*)(p0 + 8);
                u16x8 u2 = *(const u16x8*)p1, u3 = *(const u16x8*)(p1 + 8);
                u16x8 u4 = *(const u16x8*)p2, u5 = *(const u16x8*)(p2 + 8);
                u16x8 u6 = *(const u16x8*)p3, u7 = *(const u16x8*)(p3 + 8);
#pragma unroll
                for (int j = 0; j < 8; j++) {
                    a[j]     += bf2f(u0[j]) + n1 * bf2f(u2[j]) + n2 * bf2f(u4[j]) + n3 * bf2f(u6[j]);
                    a[8 + j] += bf2f(u1[j]) + n1 * bf2f(u3[j]) + n2 * bf2f(u5[j]) + n3 * bf2f(u7[j]);
                }
            }
        }
        float inv = (c > 0) ? 1.f / (float)c : 0.f;
        u16x8 w0, w1;
#pragma unroll
        for (int j = 0; j < 8; j++) { w0[j] = f2bf(a[j] * inv); w1[j] = f2bf(a[8 + j] * inv); }
        // swizzled LDS write: slot (row, p^(row&7)) holds global part p  (matches af read)
        int s0 = ((2 * td) ^ (gi & 7)) * 8;
        int s1 = ((2 * td + 1) ^ (gi & 7)) * 8;
        *(u16x8*)&as[gi * 64 + s0] = w0;
        *(u16x8*)&as[gi * 64 + s1] = w1;
    };

    auto issue_B = [&](int k, short* bs) {
        int k0 = k * BKg;
#pragma unroll
        for (int h = 0; h < 4; h++) {
            int c = t + h * 256;
            int r = c >> 3, pl = c & 7, pg = pl ^ (r & 7);
            const unsigned short* gb = Bg + (size_t)(ncol0 + r) * KDIM + k0 + pg * 8;
            __builtin_amdgcn_global_load_lds(
                (const __attribute__((address_space(1))) void*)gb,
                (__attribute__((address_space(3))) void*)((char*)bs + c * 16),
                16, 0, 0);
        }
    };
    auto issue_Aself = [&](int k, short* as) {
        int kk = k * BKg - KMEAN;
#pragma unroll
        for (int h = 0; h < 2; h++) {
            int c = t + h * 256;
            int r = c >> 3, pl = c & 7, pg = pl ^ (r & 7);
            const unsigned short* ga = fu + (row0 + r) * DIM + kk + pg * 8;
            __builtin_amdgcn_global_load_lds(
                (const __attribute__((address_space(1))) void*)ga,
                (__attribute__((address_space(3))) void*)((char*)as + c * 16),
                16, 0, 0);
        }
    };

    // ---- prologue: stage step 0 ----
    {
        G8 g0;
        g_issue(0, g0);
        issue_B(0, Bs[0]);
        g_finish(0, g0, As[0]);
        asm volatile("s_waitcnt vmcnt(0)" ::: "memory");
        asm volatile("s_waitcnt lgkmcnt(0)" ::: "memory");
        __builtin_amdgcn_s_barrier();
        __builtin_amdgcn_sched_barrier(0);
    }

    // ---- main loop (fully unrolled: buffer parity & relation index compile-time) ----
#pragma unroll
    for (int k = 0; k < NKS; k++) {
        const short* as_c = As[k & 1];
        const short* bs_c = Bs[k & 1];
        short* as_n = (short*)As[(k + 1) & 1];
        short* bs_n = (short*)Bs[(k + 1) & 1];
        G8 g;
        bool stage = (k + 1 < NKS);
        bool meanN = (k + 1 < 16);
        if (stage) {
            if (meanN) g_issue(k + 1, g);    // gather loads FIRST (wait leaves B flying)
            issue_B(k + 1, bs_n);
            if (!meanN) issue_Aself(k + 1, as_n);
        }
        // compute step k
#pragma unroll
        for (int ks = 0; ks < 2; ks++) {
            int p = ks * 4 + (lane >> 4);
            bf16x8 af[4], bfr[2];
#pragma unroll
            for (int mi = 0; mi < 4; mi++) {
                int m = mi * 16 + (lane & 15);
                af[mi] = *(const bf16x8*)&as_c[m * 64 + ((p ^ (m & 7)) * 8)];
            }
#pragma unroll
            for (int ni = 0; ni < 2; ni++) {
                int n = w * 32 + ni * 16 + (lane & 15);
                bfr[ni] = *(const bf16x8*)&bs_c[n * 64 + ((p ^ (n & 7)) * 8)];
            }
#pragma unroll
            for (int mi = 0; mi < 4; mi++)
#pragma unroll
                for (int ni = 0; ni < 2; ni++)
                    acc[mi][ni] = __builtin_amdgcn_mfma_f32_16x16x32_bf16(af[mi], bfr[ni], acc[mi][ni], 0, 0, 0);
        }
        if (stage && meanN) g_finish(k + 1, g, as_n);
        if (stage) asm volatile("s_waitcnt vmcnt(0)" ::: "memory");   // B issued ~500cy ago
        asm volatile("s_waitcnt lgkmcnt(0)" ::: "memory");
        __builtin_amdgcn_s_barrier();
        __builtin_amdgcn_sched_barrier(0);
    }

    // ---- fused epilogue (unchanged): C/D col=lane&15, row=(lane>>4)*4+j ----
    float a[2][5];
#pragma unroll
    for (int ni = 0; ni < 2; ni++)
#pragma unroll
        for (int s = 0; s < 5; s++) a[ni][s] = 0.f;

#pragma unroll
    for (int mi = 0; mi < 4; mi++) {
#pragma unroll
        for (int j = 0; j < 4; j++) {
            size_t row = row0 + mi * 16 + (lane >> 4) * 4 + j;
            if (row < (size_t)N) {
                fx4 wv = *(const fx4*)(wsr + row * RREL);
#pragma unroll
                for (int ni = 0; ni < 2; ni++) {
                    float v = fmaxf(acc[mi][ni][j] + bb[ni], 0.f);
                    a[ni][4] += v;
                    a[ni][0] += wv.x * v;
                    a[ni][1] += wv.y * v;
                    a[ni][2] += wv.z * v;
                    a[ni][3] += wv.w * v;
                }
            }
        }
    }
#pragma unroll
    for (int ni = 0; ni < 2; ni++) {
        int col = ncol0 + w * 32 + ni * 16 + (lane & 15);
#pragma unroll
        for (int s = 0; s < 5; s++) {
            float v = a[ni][s];
            v += __shfl_xor(v, 16, 64);
            v += __shfl_xor(v, 32, 64);
            if ((lane >> 4) == 0) atomicAdd(&sv[s * DIM + col], v);
        }
    }
}

// ---------------- collapsed layer 1 GEMV + fused linear head ----------------

__global__ __launch_bounds__(256)
void gemv_final(const float* __restrict__ sv, const float* __restrict__ W1,
                const float* __restrict__ root1, const float* __restrict__ b1,
                int N, float* __restrict__ g, int* __restrict__ done,
                const float* __restrict__ lw, const float* __restrict__ lb,
                float* __restrict__ out, int nblk) {
    int t = threadIdx.x;
    int kk0 = blockIdx.x * 8;
    float acc = 0.f;
#pragma unroll
    for (int u = 0; u < 8; u++) {
        int kk = kk0 + u;
        int r = kk >> 8;
        int k = kk & 255;
        const float* row = (r < RREL) ? (W1 + ((size_t)r * DIM + k) * DIM)
                                      : (root1 + (size_t)k * DIM);
        acc += sv[kk] * row[t];
    }
    if (blockIdx.x == 0) acc += (float)N * b1[t];
    atomicAdd(&g[t], acc);
    __threadfence();
    __shared__ int amLast;
    if (t == 0) amLast = (atomicAdd(done, 1) == nblk - 1);
    __syncthreads();
    if (!amLast) return;
    float gv = atomicAdd(&g[t], 0.f);
    __shared__ float s0[256], s1[256];
    s0[t] = gv * lw[t * 2 + 0];
    s1[t] = gv * lw[t * 2 + 1];
    __syncthreads();
    for (int off = 128; off > 0; off >>= 1) {
        if (t < off) { s0[t] += s0[t + off]; s1[t] += s1[t + off]; }
        __syncthreads();
    }
    if (t == 0) { out[0] = s0[0] + lb[0]; out[1] = s1[0] + lb[1]; }
}

// ---------------- launch ----------------

static inline char* align_up(char* p, size_t a) {
    return (char*)(((uintptr_t)p + (a - 1)) & ~(uintptr_t)(a - 1));
}

extern "C" void kernel_launch(void* const* d_in, const int* in_sizes, int n_in,
                              void* d_out, int out_size, void* d_ws, size_t ws_size,
                              hipStream_t stream) {
    const float* x     = (const float*)d_in[0];
    const int*   eidx  = (const int*)d_in[1];
    const int*   etype = (const int*)d_in[2];
    const float* W0    = (const float*)d_in[4];
    const float* root0 = (const float*)d_in[5];
    const float* b0    = (const float*)d_in[6];
    const float* W1    = (const float*)d_in[7];
    const float* root1 = (const float*)d_in[8];
    const float* b1    = (const float*)d_in[9];
    const float* lin_w = (const float*)d_in[10];
    const float* lin_b = (const float*)d_in[11];
    float* out = (float*)d_out;

    const int N = in_sizes[0] / DIM;
    const int E = in_sizes[2];
    const int RN = RREL * N;
    const int* src = eidx;
    const int* dst = eidx + E;

    const int gx = (N + BMg - 1) / BMg;
    const int Mpad = gx * BMg;

    char* w = (char*)d_ws;
    int*   counts = (int*)w;   w += (size_t)RN * 4;
    float* wsr    = (float*)w; w += (size_t)N * RREL * 4;
    float* sv     = (float*)w; w += (size_t)5 * DIM * 4;
    float* g      = (float*)w; w += 256 * 4;
    int*   done   = (int*)w;   w += 256;            // padded counter slot
    size_t zero_bytes = (size_t)RN * 4 + (size_t)N * RREL * 4 + 5 * DIM * 4 + 256 * 4 + 256;
    int* bucket = (int*)w; w += (size_t)RN * BCAP * 4;
    w = align_up(w, 16);
    __hip_bfloat16* WT = (__hip_bfloat16*)w; w += (size_t)DIM * KDIM * 2;
    w = align_up(w, 16);
    __hip_bfloat16* xb = (__hip_bfloat16*)w; w += (size_t)Mpad * DIM * 2;

    hipMemsetAsync(counts, 0, zero_bytes, stream);

    int eb = (E + 255) / 256;                 // scatter blocks
    int n4 = N * DIM / 4;
    int cb = (n4 + 255) / 256;                // cast blocks
    int wb = (KDIM / 32) * (DIM / 32);        // W0-transpose blocks (40*8)

    prep<<<eb + cb + wb, 256, 0, stream>>>(etype, src, dst, counts, bucket, N, E,
                                           x, xb, n4, W0, root0, WT, eb, cb);

    // edge weights (needs final counts; feeds fused epilogue)
    edgew<<<eb, 256, 0, stream>>>(etype, src, dst, counts, wsr, N, E);

    // fused mean-gather + GEMM + colsum epilogue -> sv  (m-blk x n-half)
    gemm_fused<<<gx * 2, 256, 0, stream>>>(xb, counts, bucket, WT, b0, wsr, sv, N);

    // collapsed layer 1 GEMV + fused linear head -> out
    int gvb = KDIM / 8;
    gemv_final<<<gvb, 256, 0, stream>>>(sv, W1, root1, b1, N, g, done,
                                        lin_w, lin_b, out, gvb);
}